// Round 1
// 117.214 us; speedup vs baseline: 1.0474x; 1.0474x over previous
//
#include <hip/hip_runtime.h>
#include <math.h>

#define NCOLS 5000
#define NF4   1250            // NCOLS / 4
#define BLOCK 256
#define NWAVES (BLOCK / 64)
#define NITER 5               // ceil(NF4 / BLOCK)
#define TOPKK 10
#define TR    3               // ceil(TOPKK / NWAVES) threshold rounds per wave
#define CAP 128               // candidate capacity (expected ~20-40/block)

// Monotone-ascending mapping float -> uint32 (total order on finite floats).
__device__ __forceinline__ unsigned mono_f32(float f) {
  unsigned u = __float_as_uint(f);
  return (u & 0x80000000u) ? ~u : (u | 0x80000000u);
}

__device__ __forceinline__ float wave_sum_f(float v) {
#pragma unroll
  for (int o = 1; o < 64; o <<= 1) v += __shfl_xor(v, o);
  return v;
}
__device__ __forceinline__ int wave_sum_i(int v) {
#pragma unroll
  for (int o = 1; o < 64; o <<= 1) v += __shfl_xor(v, o);
  return v;
}
__device__ __forceinline__ unsigned wave_max_u(unsigned v) {
#pragma unroll
  for (int o = 1; o < 64; o <<= 1) {
    unsigned w = __shfl_xor(v, o);
    v = w > v ? w : v;
  }
  return v;
}

extern "C" __global__ __launch_bounds__(BLOCK, 4)
void row_loss_kernel(const float* __restrict__ up, const float* __restrict__ down,
                     const float* __restrict__ yt, const int* __restrict__ masks,
                     float* __restrict__ out, float inv_nrows) {
  __shared__ float red_f[6][NWAVES];   // sq, sp, seyy, seyu, aspu, aspd
  __shared__ int red_i[NWAVES];        // nv partials
  __shared__ unsigned t1w_t[NWAVES];   // per-wave TR-th-largest thread-max (top)
  __shared__ unsigned t1w_b[NWAVES];   // same, bottom (~key space)
  __shared__ unsigned keys_t[CAP];     // top candidate keys
  __shared__ int      col_t[CAP];      // their column index
  __shared__ unsigned keys_b[CAP];     // bottom candidate keys (~key)
  __shared__ int      col_b[CAP];
  __shared__ int ct, cb;
  __shared__ float s_res[2];           // SU, SD

  const int tid = threadIdx.x;
  const int lane = tid & 63;
  const int wv = tid >> 6;
  const int row = blockIdx.x;
  const long long b4 = (long long)row * NF4;
  const long long base = (long long)row * NCOLS;

  const float4* up4 = (const float4*)up + b4;
  const float4* dn4 = (const float4*)down + b4;
  const float4* yt4 = (const float4*)yt + b4;
  const int4*   mk4 = (const int4*)masks + b4;

  if (tid == 0) { ct = 0; cb = 0; }

  // ---- 20 unconditional clamped vector loads, all issued upfront.
  float4 y4[NITER], u4[NITER], d4[NITER];
  int4 m4[NITER];
#pragma unroll
  for (int j = 0; j < NITER; ++j) {
    const int f = j * BLOCK + tid;
    const int fc = f < NF4 ? f : NF4 - 1;   // clamp, no branch around loads
    y4[j] = yt4[fc];
    u4[j] = up4[fc];
    d4[j] = dn4[fc];
    m4[j] = mk4[fc];
  }
  // Fence: forbid the scheduler from sinking the loads into the compute
  // loop (baseline VGPR=48 proves it did — ~1-2 loads in flight ->
  // latency-bound). All 20 dwordx4 stay outstanding; compiler inserts
  // progressive vmcnt waits as each j-batch is consumed.
  __builtin_amdgcn_sched_barrier(0);

  // ---- Single data pass: scalar sums + per-thread max keys.
  unsigned km[NITER][4];               // valid ? mono(y) : 0
  int nv_l = 0;
  float sq = 0.f, sp = 0.f, seyy = 0.f, seyu = 0.f, aspu = 0.f, aspd = 0.f;
  unsigned tmax = 0u, tbmax = 0u;
#pragma unroll
  for (int j = 0; j < NITER; ++j) {
    const bool inb = (j * BLOCK + tid) < NF4;
    const float* yp = (const float*)&y4[j];
    const float* upp = (const float*)&u4[j];
    const float* dp = (const float*)&d4[j];
    const int* mp = (const int*)&m4[j];
#pragma unroll
    for (int c = 0; c < 4; ++c) {
      const bool valid = inb && (mp[c] > 0);
      const float y = yp[c], u = upp[c], d = dp[c];
      const unsigned kd = valid ? mono_f32(y) : 0u;
      const unsigned kb = valid ? ~kd : 0u;
      km[j][c] = kd;
      tmax = kd > tmax ? kd : tmax;
      tbmax = kb > tbmax ? kb : tbmax;
      if (valid) {
        nv_l++;
        const float ey = __expf(y);
        const float eu = __expf(u);   // reused: Sp and softplus(u)
        const float ed = __expf(d);
        sq += ey;
        seyy += ey * y;
        seyu += ey * u;
        sp += eu;
        // softplus(x) = log1p(e^x); exact same form as the stable variant
        // for x<=0, and |logits| ~ N(0,1) keeps e^x finite. Guard anyway.
        aspu += (u > 15.f) ? u : __logf(1.f + eu);
        aspd += (d > 15.f) ? d : __logf(1.f + ed);
      }
    }
  }

  // ---- Wave reduces of scalars.
  nv_l = wave_sum_i(nv_l);
  sq = wave_sum_f(sq);
  sp = wave_sum_f(sp);
  seyy = wave_sum_f(seyy);
  seyu = wave_sum_f(seyu);
  aspu = wave_sum_f(aspu);
  aspd = wave_sum_f(aspd);
  if (lane == 0) {
    red_i[wv] = nv_l;
    red_f[0][wv] = sq;  red_f[1][wv] = sp;
    red_f[2][wv] = seyy; red_f[3][wv] = seyu;
    red_f[4][wv] = aspu; red_f[5][wv] = aspd;
  }

  // ---- Per-wave filter threshold, TR=3 rounds (was 10).
  // TR-th-largest thread-max per wave: >=TR threads per wave hold >=1
  // element >= t_w, so across NWAVES waves >= NWAVES*TR = 12 >= TOPKK
  // elements >= min_w(t_w). Combine across waves with MIN (was MAX of
  // per-wave-10th). Top and bottom chains interleave for ILP.
  // (Assumes every wave has >=TR threads owning >=1 valid element; each
  //  thread covers 20 elements at ~50% density -> P(fail) ~ 2^-20 scale.)
  {
    unsigned vt = tmax, vb = tbmax, t1t = 0u, t1b = 0u;
#pragma unroll
    for (int r = 0; r < TR; ++r) {
      unsigned mt = wave_max_u(vt);
      unsigned mb = wave_max_u(vb);
      if (vt == mt) vt = 0u;
      if (vb == mb) vb = 0u;
      t1t = mt; t1b = mb;
    }
    if (lane == 0) { t1w_t[wv] = t1t; t1w_b[wv] = t1b; }
  }
  __syncthreads();

  int nv = 0;
#pragma unroll
  for (int w = 0; w < NWAVES; ++w) nv += red_i[w];
  const int k = nv < TOPKK ? nv : TOPKK;

  unsigned t1 = 0xFFFFFFFFu, t1b = 0xFFFFFFFFu;
#pragma unroll
  for (int w = 0; w < NWAVES; ++w) {
    t1 = t1w_t[w] < t1 ? t1w_t[w] : t1;
    t1b = t1w_b[w] < t1b ? t1w_b[w] : t1b;
  }

  // ---- Compact candidate (key, column) pairs into LDS (~20-40 total).
#pragma unroll
  for (int j = 0; j < NITER; ++j) {
#pragma unroll
    for (int c = 0; c < 4; ++c) {
      const unsigned kd = km[j][c];
      if (kd != 0u) {
        const int col = ((j * BLOCK + tid) << 2) + c;
        if (kd >= t1) {
          int i = atomicAdd(&ct, 1);
          if (i < CAP) { keys_t[i] = kd; col_t[i] = col; }
        }
        const unsigned kb = ~kd;
        if (kb >= t1b) {
          int i = atomicAdd(&cb, 1);
          if (i < CAP) { keys_b[i] = kb; col_b[i] = col; }
        }
      }
    }
  }
  __syncthreads();

  // ---- Wave 0: exact k-th top key, then Sum u over top-k (L2-warm reload).
  if (wv == 0) {
    const int n = ct < CAP ? ct : CAP;
    unsigned k0 = (lane < n) ? keys_t[lane] : 0u;
    unsigned k1 = (64 + lane < n) ? keys_t[64 + lane] : 0u;
    unsigned w0 = k0, w1 = k1;
    unsigned thr = 0xFFFFFFFFu;
#pragma unroll 1
    for (int r = 0; r < k; ++r) {
      unsigned m = wave_max_u(w0 > w1 ? w0 : w1);
      if (w0 == m) w0 = 0u;
      else if (w1 == m) w1 = 0u;
      thr = m;
    }
    float su = 0.f;
    if (k0 >= thr && k0 != 0u) su += up[base + col_t[lane]];
    if (k1 >= thr && k1 != 0u) su += up[base + col_t[64 + lane]];
    su = wave_sum_f(su);
    if (lane == 0) s_res[0] = su;
  } else if (wv == 1) {
    // ---- Wave 1: exact k-th bottom key, Sum d over bottom-k.
    const int n = cb < CAP ? cb : CAP;
    unsigned k0 = (lane < n) ? keys_b[lane] : 0u;
    unsigned k1 = (64 + lane < n) ? keys_b[64 + lane] : 0u;
    unsigned w0 = k0, w1 = k1;
    unsigned thr = 0xFFFFFFFFu;
#pragma unroll 1
    for (int r = 0; r < k; ++r) {
      unsigned m = wave_max_u(w0 > w1 ? w0 : w1);
      if (w0 == m) w0 = 0u;
      else if (w1 == m) w1 = 0u;
      thr = m;
    }
    float sd = 0.f;
    if (k0 >= thr && k0 != 0u) sd += down[base + col_b[lane]];
    if (k1 >= thr && k1 != 0u) sd += down[base + col_b[64 + lane]];
    sd = wave_sum_f(sd);
    if (lane == 0) s_res[1] = sd;
  }
  __syncthreads();

  if (tid == 0 && nv > 0) {
    float SQ = 0.f, SP = 0.f, SYY = 0.f, SYU = 0.f, ASU = 0.f, ASD = 0.f;
#pragma unroll
    for (int w = 0; w < NWAVES; ++w) {
      SQ += red_f[0][w]; SP += red_f[1][w];
      SYY += red_f[2][w]; SYU += red_f[3][w];
      ASU += red_f[4][w]; ASD += red_f[5][w];
    }
    const float SU = s_res[0];
    const float SD = s_res[1];
    // KL closed form: sum q*(logq - logp) = (Seyy - Seyu)/Sq - log(Sq) + log(Sp)
    const float kl = (SYY - SYU) / SQ - __logf(SQ) + __logf(SP);
    const float up_loss = ASU - SU;  // sum softplus(u) - sum_{topk} u
    const float dn_loss = ASD - SD;  // sum softplus(d) - sum_{botk} d
    const float loss = (up_loss + 0.5f * dn_loss + 0.3f * kl) / (float)nv;
    atomicAdd(out, loss * inv_nrows);
  }
}

extern "C" void kernel_launch(void* const* d_in, const int* in_sizes, int n_in,
                              void* d_out, int out_size, void* d_ws, size_t ws_size,
                              hipStream_t stream) {
  const float* up_logits   = (const float*)d_in[0];
  const float* down_logits = (const float*)d_in[1];
  const float* y_true      = (const float*)d_in[2];
  const int*   masks       = (const int*)d_in[3];

  const int nrows = in_sizes[0] / NCOLS;

  hipMemsetAsync(d_out, 0, sizeof(float) * (size_t)out_size, stream);
  row_loss_kernel<<<nrows, BLOCK, 0, stream>>>(up_logits, down_logits, y_true,
                                               masks, (float*)d_out,
                                               1.0f / (float)nrows);
}

// Round 2
// 116.478 us; speedup vs baseline: 1.0540x; 1.0063x over previous
//
#include <hip/hip_runtime.h>
#include <math.h>

#define NCOLS 5000
#define NF4   1250            // NCOLS / 4
#define BLOCK 256
#define NWAVES (BLOCK / 64)
#define NITER 5               // ceil(NF4 / BLOCK)
#define TOPKK 10
#define TR    3               // ceil(TOPKK / NWAVES) threshold rounds per wave
#define CAP 128               // candidate capacity (expected ~20-40/block)

// Monotone-ascending mapping float -> uint32 (total order on finite floats).
__device__ __forceinline__ unsigned mono_f32(float f) {
  unsigned u = __float_as_uint(f);
  return (u & 0x80000000u) ? ~u : (u | 0x80000000u);
}

__device__ __forceinline__ float wave_sum_f(float v) {
#pragma unroll
  for (int o = 1; o < 64; o <<= 1) v += __shfl_xor(v, o);
  return v;
}
__device__ __forceinline__ int wave_sum_i(int v) {
#pragma unroll
  for (int o = 1; o < 64; o <<= 1) v += __shfl_xor(v, o);
  return v;
}
__device__ __forceinline__ unsigned wave_max_u(unsigned v) {
#pragma unroll
  for (int o = 1; o < 64; o <<= 1) {
    unsigned w = __shfl_xor(v, o);
    v = w > v ? w : v;
  }
  return v;
}

extern "C" __global__ __launch_bounds__(BLOCK, 4)
void row_loss_kernel(const float* __restrict__ up, const float* __restrict__ down,
                     const float* __restrict__ yt, const int* __restrict__ masks,
                     float* __restrict__ out, float inv_nrows) {
  // km staged in LDS instead of 20 VGPRs: per-thread-private slots, stride-16
  // ds_write_b128/ds_read_b128 (conflict-free), no barrier needed (each thread
  // touches only its own slot). Frees the register allocator from the 128-cap
  // spill zone while keeping all 20 global loads resident upfront.
  __shared__ uint4 km_s[NITER * BLOCK];  // 20 KB
  __shared__ float red_f[6][NWAVES];   // sq, sp, seyy, seyu, aspu, aspd
  __shared__ int red_i[NWAVES];        // nv partials
  __shared__ unsigned t1w_t[NWAVES];   // per-wave TR-th-largest thread-max (top)
  __shared__ unsigned t1w_b[NWAVES];   // same, bottom (~key space)
  __shared__ unsigned keys_t[CAP];     // top candidate keys
  __shared__ int      col_t[CAP];      // their column index
  __shared__ unsigned keys_b[CAP];     // bottom candidate keys (~key)
  __shared__ int      col_b[CAP];
  __shared__ int ct, cb;
  __shared__ float s_res[2];           // SU, SD

  const int tid = threadIdx.x;
  const int lane = tid & 63;
  const int wv = tid >> 6;
  const int row = blockIdx.x;
  const long long b4 = (long long)row * NF4;
  const long long base = (long long)row * NCOLS;

  const float4* up4 = (const float4*)up + b4;
  const float4* dn4 = (const float4*)down + b4;
  const float4* yt4 = (const float4*)yt + b4;
  const int4*   mk4 = (const int4*)masks + b4;

  if (tid == 0) { ct = 0; cb = 0; }

  // ---- 20 unconditional clamped vector loads, all issued upfront.
  float4 y4[NITER], u4[NITER], d4[NITER];
  int4 m4[NITER];
#pragma unroll
  for (int j = 0; j < NITER; ++j) {
    const int f = j * BLOCK + tid;
    const int fc = f < NF4 ? f : NF4 - 1;   // clamp, no branch around loads
    y4[j] = yt4[fc];
    u4[j] = up4[fc];
    d4[j] = dn4[fc];
    m4[j] = mk4[fc];
  }
  // Fence: forbid the scheduler from sinking the loads into the compute loop.
  __builtin_amdgcn_sched_barrier(0);

  // ---- Single data pass: scalar sums + per-thread max keys.
  int nv_l = 0;
  float sq = 0.f, sp = 0.f, seyy = 0.f, seyu = 0.f, aspu = 0.f, aspd = 0.f;
  unsigned tmax = 0u, tbmax = 0u;
#pragma unroll
  for (int j = 0; j < NITER; ++j) {
    const bool inb = (j * BLOCK + tid) < NF4;
    const float* yp = (const float*)&y4[j];
    const float* upp = (const float*)&u4[j];
    const float* dp = (const float*)&d4[j];
    const int* mp = (const int*)&m4[j];
    unsigned kk[4];
#pragma unroll
    for (int c = 0; c < 4; ++c) {
      const bool valid = inb && (mp[c] > 0);
      const float y = yp[c], u = upp[c], d = dp[c];
      const unsigned kd = valid ? mono_f32(y) : 0u;
      const unsigned kb = valid ? ~kd : 0u;
      kk[c] = kd;
      tmax = kd > tmax ? kd : tmax;
      tbmax = kb > tbmax ? kb : tbmax;
      if (valid) {
        nv_l++;
        const float ey = __expf(y);
        const float eu = __expf(u);   // reused: Sp and softplus(u)
        const float ed = __expf(d);
        sq += ey;
        seyy += ey * y;
        seyu += ey * u;
        sp += eu;
        aspu += (u > 15.f) ? u : __logf(1.f + eu);
        aspd += (d > 15.f) ? d : __logf(1.f + ed);
      }
    }
    km_s[j * BLOCK + tid] = make_uint4(kk[0], kk[1], kk[2], kk[3]);
  }

  // ---- Wave reduces of scalars.
  nv_l = wave_sum_i(nv_l);
  sq = wave_sum_f(sq);
  sp = wave_sum_f(sp);
  seyy = wave_sum_f(seyy);
  seyu = wave_sum_f(seyu);
  aspu = wave_sum_f(aspu);
  aspd = wave_sum_f(aspd);
  if (lane == 0) {
    red_i[wv] = nv_l;
    red_f[0][wv] = sq;  red_f[1][wv] = sp;
    red_f[2][wv] = seyy; red_f[3][wv] = seyu;
    red_f[4][wv] = aspu; red_f[5][wv] = aspd;
  }

  // ---- Per-wave filter threshold, TR=3 rounds.
  // TR-th-largest thread-max per wave; across NWAVES waves >= 12 >= TOPKK
  // elements >= min_w(t_w). Top and bottom chains interleave for ILP.
  {
    unsigned vt = tmax, vb = tbmax, t1t = 0u, t1b = 0u;
#pragma unroll
    for (int r = 0; r < TR; ++r) {
      unsigned mt = wave_max_u(vt);
      unsigned mb = wave_max_u(vb);
      if (vt == mt) vt = 0u;
      if (vb == mb) vb = 0u;
      t1t = mt; t1b = mb;
    }
    if (lane == 0) { t1w_t[wv] = t1t; t1w_b[wv] = t1b; }
  }
  __syncthreads();

  int nv = 0;
#pragma unroll
  for (int w = 0; w < NWAVES; ++w) nv += red_i[w];
  const int k = nv < TOPKK ? nv : TOPKK;

  unsigned t1 = 0xFFFFFFFFu, t1b = 0xFFFFFFFFu;
#pragma unroll
  for (int w = 0; w < NWAVES; ++w) {
    t1 = t1w_t[w] < t1 ? t1w_t[w] : t1;
    t1b = t1w_b[w] < t1b ? t1w_b[w] : t1b;
  }

  // ---- Compact candidate (key, column) pairs into LDS (~20-40 total).
#pragma unroll
  for (int j = 0; j < NITER; ++j) {
    const uint4 kk4 = km_s[j * BLOCK + tid];
    const unsigned ka[4] = {kk4.x, kk4.y, kk4.z, kk4.w};
#pragma unroll
    for (int c = 0; c < 4; ++c) {
      const unsigned kd = ka[c];
      if (kd != 0u) {
        const int col = ((j * BLOCK + tid) << 2) + c;
        if (kd >= t1) {
          int i = atomicAdd(&ct, 1);
          if (i < CAP) { keys_t[i] = kd; col_t[i] = col; }
        }
        const unsigned kb = ~kd;
        if (kb >= t1b) {
          int i = atomicAdd(&cb, 1);
          if (i < CAP) { keys_b[i] = kb; col_b[i] = col; }
        }
      }
    }
  }
  __syncthreads();

  // ---- Waves 0/1: exact k-th key via 32-step ballot binary search
  // (replaces k dependent wave-max rounds; same tie semantics: sum over all
  // keys >= thr where thr = k-th largest key).
  if (wv == 0) {
    const int n = ct < CAP ? ct : CAP;
    const unsigned k0 = (lane < n) ? keys_t[lane] : 0u;
    const unsigned k1 = (64 + lane < n) ? keys_t[64 + lane] : 0u;
    unsigned thr = 0u;
#pragma unroll
    for (int b = 31; b >= 0; --b) {
      const unsigned t = thr | (1u << b);
      const int c = __popcll(__ballot(k0 >= t)) + __popcll(__ballot(k1 >= t));
      thr = (c >= k) ? t : thr;
    }
    float su = 0.f;
    if (k0 >= thr && k0 != 0u) su += up[base + col_t[lane]];
    if (k1 >= thr && k1 != 0u) su += up[base + col_t[64 + lane]];
    su = wave_sum_f(su);
    if (lane == 0) s_res[0] = su;
  } else if (wv == 1) {
    const int n = cb < CAP ? cb : CAP;
    const unsigned k0 = (lane < n) ? keys_b[lane] : 0u;
    const unsigned k1 = (64 + lane < n) ? keys_b[64 + lane] : 0u;
    unsigned thr = 0u;
#pragma unroll
    for (int b = 31; b >= 0; --b) {
      const unsigned t = thr | (1u << b);
      const int c = __popcll(__ballot(k0 >= t)) + __popcll(__ballot(k1 >= t));
      thr = (c >= k) ? t : thr;
    }
    float sd = 0.f;
    if (k0 >= thr && k0 != 0u) sd += down[base + col_b[lane]];
    if (k1 >= thr && k1 != 0u) sd += down[base + col_b[64 + lane]];
    sd = wave_sum_f(sd);
    if (lane == 0) s_res[1] = sd;
  }
  __syncthreads();

  if (tid == 0 && nv > 0) {
    float SQ = 0.f, SP = 0.f, SYY = 0.f, SYU = 0.f, ASU = 0.f, ASD = 0.f;
#pragma unroll
    for (int w = 0; w < NWAVES; ++w) {
      SQ += red_f[0][w]; SP += red_f[1][w];
      SYY += red_f[2][w]; SYU += red_f[3][w];
      ASU += red_f[4][w]; ASD += red_f[5][w];
    }
    const float SU = s_res[0];
    const float SD = s_res[1];
    // KL closed form: sum q*(logq - logp) = (Seyy - Seyu)/Sq - log(Sq) + log(Sp)
    const float kl = (SYY - SYU) / SQ - __logf(SQ) + __logf(SP);
    const float up_loss = ASU - SU;  // sum softplus(u) - sum_{topk} u
    const float dn_loss = ASD - SD;  // sum softplus(d) - sum_{botk} d
    const float loss = (up_loss + 0.5f * dn_loss + 0.3f * kl) / (float)nv;
    atomicAdd(out, loss * inv_nrows);
  }
}

extern "C" void kernel_launch(void* const* d_in, const int* in_sizes, int n_in,
                              void* d_out, int out_size, void* d_ws, size_t ws_size,
                              hipStream_t stream) {
  const float* up_logits   = (const float*)d_in[0];
  const float* down_logits = (const float*)d_in[1];
  const float* y_true      = (const float*)d_in[2];
  const int*   masks       = (const int*)d_in[3];

  const int nrows = in_sizes[0] / NCOLS;

  hipMemsetAsync(d_out, 0, sizeof(float) * (size_t)out_size, stream);
  row_loss_kernel<<<nrows, BLOCK, 0, stream>>>(up_logits, down_logits, y_true,
                                               masks, (float*)d_out,
                                               1.0f / (float)nrows);
}

// Round 3
// 115.350 us; speedup vs baseline: 1.0643x; 1.0098x over previous
//
#include <hip/hip_runtime.h>
#include <math.h>

#define NCOLS 5000
#define NF4   1250            // NCOLS / 4
#define BLOCK 256
#define NWAVES (BLOCK / 64)
#define NITER 5               // ceil(NF4 / BLOCK)
#define TOPKK 10
#define TR    3               // ceil(TOPKK / NWAVES) threshold rounds per wave
#define CAP 128               // candidate capacity (expected ~20-40/block)

// Monotone-ascending mapping float -> uint32 (total order on finite floats).
__device__ __forceinline__ unsigned mono_f32(float f) {
  unsigned u = __float_as_uint(f);
  return (u & 0x80000000u) ? ~u : (u | 0x80000000u);
}

__device__ __forceinline__ float wave_sum_f(float v) {
#pragma unroll
  for (int o = 1; o < 64; o <<= 1) v += __shfl_xor(v, o);
  return v;
}
__device__ __forceinline__ int wave_sum_i(int v) {
#pragma unroll
  for (int o = 1; o < 64; o <<= 1) v += __shfl_xor(v, o);
  return v;
}
__device__ __forceinline__ unsigned wave_max_u(unsigned v) {
#pragma unroll
  for (int o = 1; o < 64; o <<= 1) {
    unsigned w = __shfl_xor(v, o);
    v = w > v ? w : v;
  }
  return v;
}

// use_ws != 0 : plain store of per-row loss to ws[row]; reducer kernel sums.
//               (kills the 1024-block same-address atomic completion tail)
// use_ws == 0 : legacy atomicAdd fallback (workspace too small).
extern "C" __global__ __launch_bounds__(BLOCK, 4)
void row_loss_kernel(const float* __restrict__ up, const float* __restrict__ down,
                     const float* __restrict__ yt, const int* __restrict__ masks,
                     float* __restrict__ ws, float* __restrict__ out,
                     float inv_nrows, int use_ws) {
  __shared__ uint4 km_s[NITER * BLOCK];  // 20 KB per-thread-private key slots
  __shared__ float red_f[6][NWAVES];   // sq, sp, seyy, seyu, aspu, aspd
  __shared__ int red_i[NWAVES];        // nv partials
  __shared__ unsigned t1w_t[NWAVES];   // per-wave TR-th-largest thread-max (top)
  __shared__ unsigned t1w_b[NWAVES];   // same, bottom (~key space)
  __shared__ unsigned keys_t[CAP];     // top candidate keys
  __shared__ int      col_t[CAP];      // their column index
  __shared__ unsigned keys_b[CAP];     // bottom candidate keys (~key)
  __shared__ int      col_b[CAP];
  __shared__ int ct, cb;
  __shared__ float s_res[2];           // SU, SD

  const int tid = threadIdx.x;
  const int lane = tid & 63;
  const int wv = tid >> 6;
  const int row = blockIdx.x;
  const long long b4 = (long long)row * NF4;
  const long long base = (long long)row * NCOLS;

  const float4* up4 = (const float4*)up + b4;
  const float4* dn4 = (const float4*)down + b4;
  const float4* yt4 = (const float4*)yt + b4;
  const int4*   mk4 = (const int4*)masks + b4;

  if (tid == 0) { ct = 0; cb = 0; }

  // ---- 20 unconditional clamped vector loads, all issued upfront.
  float4 y4[NITER], u4[NITER], d4[NITER];
  int4 m4[NITER];
#pragma unroll
  for (int j = 0; j < NITER; ++j) {
    const int f = j * BLOCK + tid;
    const int fc = f < NF4 ? f : NF4 - 1;   // clamp, no branch around loads
    y4[j] = yt4[fc];
    u4[j] = up4[fc];
    d4[j] = dn4[fc];
    m4[j] = mk4[fc];
  }
  // Fence: forbid the scheduler from sinking the loads into the compute loop.
  __builtin_amdgcn_sched_barrier(0);

  // ---- Single data pass: scalar sums + per-thread max keys.
  int nv_l = 0;
  float sq = 0.f, sp = 0.f, seyy = 0.f, seyu = 0.f, aspu = 0.f, aspd = 0.f;
  unsigned tmax = 0u, tbmax = 0u;
#pragma unroll
  for (int j = 0; j < NITER; ++j) {
    const bool inb = (j * BLOCK + tid) < NF4;
    const float* yp = (const float*)&y4[j];
    const float* upp = (const float*)&u4[j];
    const float* dp = (const float*)&d4[j];
    const int* mp = (const int*)&m4[j];
    unsigned kk[4];
#pragma unroll
    for (int c = 0; c < 4; ++c) {
      const bool valid = inb && (mp[c] > 0);
      const float y = yp[c], u = upp[c], d = dp[c];
      const unsigned kd = valid ? mono_f32(y) : 0u;
      const unsigned kb = valid ? ~kd : 0u;
      kk[c] = kd;
      tmax = kd > tmax ? kd : tmax;
      tbmax = kb > tbmax ? kb : tbmax;
      if (valid) {
        nv_l++;
        const float ey = __expf(y);
        const float eu = __expf(u);   // reused: Sp and softplus(u)
        const float ed = __expf(d);
        sq += ey;
        seyy += ey * y;
        seyu += ey * u;
        sp += eu;
        aspu += (u > 15.f) ? u : __logf(1.f + eu);
        aspd += (d > 15.f) ? d : __logf(1.f + ed);
      }
    }
    km_s[j * BLOCK + tid] = make_uint4(kk[0], kk[1], kk[2], kk[3]);
  }

  // ---- Wave reduces of scalars.
  nv_l = wave_sum_i(nv_l);
  sq = wave_sum_f(sq);
  sp = wave_sum_f(sp);
  seyy = wave_sum_f(seyy);
  seyu = wave_sum_f(seyu);
  aspu = wave_sum_f(aspu);
  aspd = wave_sum_f(aspd);
  if (lane == 0) {
    red_i[wv] = nv_l;
    red_f[0][wv] = sq;  red_f[1][wv] = sp;
    red_f[2][wv] = seyy; red_f[3][wv] = seyu;
    red_f[4][wv] = aspu; red_f[5][wv] = aspd;
  }

  // ---- Per-wave filter threshold, TR=3 rounds.
  // TR-th-largest thread-max per wave; across NWAVES waves >= 12 >= TOPKK
  // elements >= min_w(t_w). Top and bottom chains interleave for ILP.
  {
    unsigned vt = tmax, vb = tbmax, t1t = 0u, t1b = 0u;
#pragma unroll
    for (int r = 0; r < TR; ++r) {
      unsigned mt = wave_max_u(vt);
      unsigned mb = wave_max_u(vb);
      if (vt == mt) vt = 0u;
      if (vb == mb) vb = 0u;
      t1t = mt; t1b = mb;
    }
    if (lane == 0) { t1w_t[wv] = t1t; t1w_b[wv] = t1b; }
  }
  __syncthreads();

  int nv = 0;
#pragma unroll
  for (int w = 0; w < NWAVES; ++w) nv += red_i[w];
  const int k = nv < TOPKK ? nv : TOPKK;

  unsigned t1 = 0xFFFFFFFFu, t1b = 0xFFFFFFFFu;
#pragma unroll
  for (int w = 0; w < NWAVES; ++w) {
    t1 = t1w_t[w] < t1 ? t1w_t[w] : t1;
    t1b = t1w_b[w] < t1b ? t1w_b[w] : t1b;
  }

  // ---- Compact candidate (key, column) pairs into LDS (~20-40 total).
#pragma unroll
  for (int j = 0; j < NITER; ++j) {
    const uint4 kk4 = km_s[j * BLOCK + tid];
    const unsigned ka[4] = {kk4.x, kk4.y, kk4.z, kk4.w};
#pragma unroll
    for (int c = 0; c < 4; ++c) {
      const unsigned kd = ka[c];
      if (kd != 0u) {
        const int col = ((j * BLOCK + tid) << 2) + c;
        if (kd >= t1) {
          int i = atomicAdd(&ct, 1);
          if (i < CAP) { keys_t[i] = kd; col_t[i] = col; }
        }
        const unsigned kb = ~kd;
        if (kb >= t1b) {
          int i = atomicAdd(&cb, 1);
          if (i < CAP) { keys_b[i] = kb; col_b[i] = col; }
        }
      }
    }
  }
  __syncthreads();

  // ---- Waves 0/1: exact k-th key via 32-step ballot binary search.
  if (wv == 0) {
    const int n = ct < CAP ? ct : CAP;
    const unsigned k0 = (lane < n) ? keys_t[lane] : 0u;
    const unsigned k1 = (64 + lane < n) ? keys_t[64 + lane] : 0u;
    unsigned thr = 0u;
#pragma unroll
    for (int b = 31; b >= 0; --b) {
      const unsigned t = thr | (1u << b);
      const int c = __popcll(__ballot(k0 >= t)) + __popcll(__ballot(k1 >= t));
      thr = (c >= k) ? t : thr;
    }
    float su = 0.f;
    if (k0 >= thr && k0 != 0u) su += up[base + col_t[lane]];
    if (k1 >= thr && k1 != 0u) su += up[base + col_t[64 + lane]];
    su = wave_sum_f(su);
    if (lane == 0) s_res[0] = su;
  } else if (wv == 1) {
    const int n = cb < CAP ? cb : CAP;
    const unsigned k0 = (lane < n) ? keys_b[lane] : 0u;
    const unsigned k1 = (64 + lane < n) ? keys_b[64 + lane] : 0u;
    unsigned thr = 0u;
#pragma unroll
    for (int b = 31; b >= 0; --b) {
      const unsigned t = thr | (1u << b);
      const int c = __popcll(__ballot(k0 >= t)) + __popcll(__ballot(k1 >= t));
      thr = (c >= k) ? t : thr;
    }
    float sd = 0.f;
    if (k0 >= thr && k0 != 0u) sd += down[base + col_b[lane]];
    if (k1 >= thr && k1 != 0u) sd += down[base + col_b[64 + lane]];
    sd = wave_sum_f(sd);
    if (lane == 0) s_res[1] = sd;
  }
  __syncthreads();

  if (tid == 0) {
    float loss = 0.f;
    if (nv > 0) {
      float SQ = 0.f, SP = 0.f, SYY = 0.f, SYU = 0.f, ASU = 0.f, ASD = 0.f;
#pragma unroll
      for (int w = 0; w < NWAVES; ++w) {
        SQ += red_f[0][w]; SP += red_f[1][w];
        SYY += red_f[2][w]; SYU += red_f[3][w];
        ASU += red_f[4][w]; ASD += red_f[5][w];
      }
      const float SU = s_res[0];
      const float SD = s_res[1];
      // KL closed form: sum q*(logq-logp) = (Seyy-Seyu)/Sq - log(Sq) + log(Sp)
      const float kl = (SYY - SYU) / SQ - __logf(SQ) + __logf(SP);
      const float up_loss = ASU - SU;  // sum softplus(u) - sum_{topk} u
      const float dn_loss = ASD - SD;  // sum softplus(d) - sum_{botk} d
      loss = (up_loss + 0.5f * dn_loss + 0.3f * kl) / (float)nv;
    }
    if (use_ws) {
      ws[row] = loss;                       // plain store, no serialization
    } else if (loss != 0.f) {
      atomicAdd(out, loss * inv_nrows);     // legacy fallback
    }
  }
}

// Deterministic 1-block tree reduction of the per-row losses.
extern "C" __global__ __launch_bounds__(256)
void reduce_loss_kernel(const float* __restrict__ ws, float* __restrict__ out,
                        int n, float inv_n) {
  __shared__ float part[4];
  const int tid = threadIdx.x;
  const int lane = tid & 63;
  const int wv = tid >> 6;
  float s = 0.f;
  const int n4 = n >> 2;
  const float4* w4 = (const float4*)ws;
  for (int i = tid; i < n4; i += 256) {
    const float4 v = w4[i];
    s += (v.x + v.y) + (v.z + v.w);
  }
  for (int i = (n4 << 2) + tid; i < n; i += 256) s += ws[i];
  s = wave_sum_f(s);
  if (lane == 0) part[wv] = s;
  __syncthreads();
  if (tid == 0) out[0] = (part[0] + part[1] + part[2] + part[3]) * inv_n;
}

extern "C" void kernel_launch(void* const* d_in, const int* in_sizes, int n_in,
                              void* d_out, int out_size, void* d_ws, size_t ws_size,
                              hipStream_t stream) {
  const float* up_logits   = (const float*)d_in[0];
  const float* down_logits = (const float*)d_in[1];
  const float* y_true      = (const float*)d_in[2];
  const int*   masks       = (const int*)d_in[3];

  const int nrows = in_sizes[0] / NCOLS;
  const int use_ws = (d_ws != nullptr && ws_size >= (size_t)nrows * sizeof(float)) ? 1 : 0;

  hipMemsetAsync(d_out, 0, sizeof(float) * (size_t)out_size, stream);
  row_loss_kernel<<<nrows, BLOCK, 0, stream>>>(up_logits, down_logits, y_true,
                                               masks, (float*)d_ws, (float*)d_out,
                                               1.0f / (float)nrows, use_ws);
  if (use_ws) {
    reduce_loss_kernel<<<1, 256, 0, stream>>>((const float*)d_ws, (float*)d_out,
                                              nrows, 1.0f / (float)nrows);
  }
}